// Round 9
// baseline (64.692 us; speedup 1.0000x reference)
//
#include <hip/hip_runtime.h>

// cluster (discriminative) loss: L_var + L_dist, C=4, K=5.
// SINGLE cooperative kernel: pixels stay in REGISTERS across both phases
// (eliminates the 40MB second read). In-kernel barrier:
//   publish: atomicExch to distinct lines (proven cheap, R6)
//   arrive:  hierarchical 32x32 ticket (R6 lesson: flat 1024-RMW = ~28us)
//   wait:    __hip_atomic_load polling (concurrent reads, not RMWs)
//   acquire: __threadfence() ONLY in the one reducing block (R4 lesson:
//            mass threadfence = full-L2 wb/inv storms, +100us)
// Cooperative launch guarantees co-residency -> spin is deadlock-free.
// Fallback: proven round-3 4-kernel pipeline if cooperative launch fails.

constexpr int K   = 5;
constexpr int C   = 4;
constexpr int TPB = 256;
constexpr int PPT = 8;
constexpr int NB  = 1024;      // 1024*256*8 = 2^21 = HW exactly
constexpr int NGROUP  = 32;
constexpr int GSTRIDE = 16;    // 64B between group tickets

__device__ __forceinline__ float wave_reduce_sum(float v) {
#pragma unroll
  for (int off = 32; off > 0; off >>= 1) v += __shfl_down(v, off, 64);
  return v;
}

// Sum one column of nb floats (nb multiple of 256) with one wave.
__device__ __forceinline__ float wave_col_sum(const float* __restrict__ colp,
                                              int lane, int nb) {
  const float4* p4 = reinterpret_cast<const float4*>(colp);
  float s = 0.f;
  for (int r = lane; r < (nb >> 2); r += 64) {
    float4 a = p4[r];
    s += (a.x + a.y) + (a.z + a.w);
  }
  return wave_reduce_sum(s);
}

__device__ __forceinline__ bool hier_arrive_last(int* __restrict__ gtick,
                                                 int* __restrict__ stick,
                                                 int bid, int nb) {
  const int g = atomicAdd(&gtick[(bid & (NGROUP - 1)) * GSTRIDE], 1);
  if (g == nb / NGROUP - 1) {
    return atomicAdd(stick, 1) == NGROUP - 1;
  }
  return false;
}

// ======================= fused cooperative kernel =======================
__global__ __launch_bounds__(TPB, 4) void k_fused(
    const float* __restrict__ pred, const int* __restrict__ lab,
    const float* __restrict__ dv_p, const float* __restrict__ dd_p,
    float* __restrict__ partial, float* __restrict__ finals,
    float* __restrict__ vpart, int* __restrict__ bar,
    float* __restrict__ out, int HW) {
  const int tid = threadIdx.x, bid = blockIdx.x;
  const int wave = tid >> 6, lane = tid & 63;
  const int nb = gridDim.x;

  int* gtick1 = bar;
  int* stick1 = bar + NGROUP * GSTRIDE;
  int* flag1  = bar + NGROUP * GSTRIDE + 16;
  int* gtick2 = bar + NGROUP * GSTRIDE + 32;
  int* stick2 = bar + 2 * NGROUP * GSTRIDE + 32;

  // ---------- Phase A: load ONCE into registers; per-thread stats ----------
  const long long p0 = ((long long)bid * TPB + tid) * PPT;
  float x[PPT][C];
  int labv[PPT];
  if (p0 + PPT <= HW) {
    int4 la = *reinterpret_cast<const int4*>(lab + p0);
    int4 lb = *reinterpret_cast<const int4*>(lab + p0 + 4);
    labv[0]=la.x; labv[1]=la.y; labv[2]=la.z; labv[3]=la.w;
    labv[4]=lb.x; labv[5]=lb.y; labv[6]=lb.z; labv[7]=lb.w;
#pragma unroll
    for (int c = 0; c < C; ++c) {
      const float* base = pred + (long long)c * HW + p0;
      float4 a = *reinterpret_cast<const float4*>(base);
      float4 b = *reinterpret_cast<const float4*>(base + 4);
      x[0][c]=a.x; x[1][c]=a.y; x[2][c]=a.z; x[3][c]=a.w;
      x[4][c]=b.x; x[5][c]=b.y; x[6][c]=b.z; x[7][c]=b.w;
    }
  } else {
#pragma unroll
    for (int p = 0; p < PPT; ++p) {
      if (p0 + p < HW) {
        labv[p] = lab[p0 + p];
#pragma unroll
        for (int c = 0; c < C; ++c) x[p][c] = pred[(long long)c * HW + p0 + p];
      } else {
        labv[p] = -1;
#pragma unroll
        for (int c = 0; c < C; ++c) x[p][c] = 0.f;
      }
    }
  }

  float cnt[K] = {0.f, 0.f, 0.f, 0.f, 0.f};
  float sum[K][C] = {};
#pragma unroll
  for (int p = 0; p < PPT; ++p) {
    const int l = labv[p];
#pragma unroll
    for (int k = 0; k < K; ++k) {
      const float m = (l == k) ? 1.0f : 0.0f;
      cnt[k] += m;
#pragma unroll
      for (int c = 0; c < C; ++c) sum[k][c] = fmaf(m, x[p][c], sum[k][c]);
    }
  }

  // block reduce 25 -> publish partial column
  __shared__ float red[TPB / 64][25];
#pragma unroll
  for (int j = 0; j < 25; ++j) {
    float v = (j < K) ? cnt[j] : sum[(j - K) >> 2][(j - K) & 3];
    v = wave_reduce_sum(v);
    if (lane == 0) red[wave][j] = v;
  }
  __syncthreads();
  if (tid < 25) {
    float t = red[0][tid] + red[1][tid] + red[2][tid] + red[3][tid];
    atomicExch(&partial[tid * nb + bid], t);  // publish at coherence point
  }
  __syncthreads();  // drains vmcnt(0): exchanges complete before arrive

  // ---------- Barrier A: last block computes centroids + L_dist ----------
  __shared__ int lastA;
  if (tid == 0) lastA = hier_arrive_last(gtick1, stick1, bid, nb) ? 1 : 0;
  __syncthreads();
  if (lastA) {
    __threadfence();  // acquire (this block only)
    __shared__ float tot[25];
    for (int col = wave; col < 25; col += TPB / 64) {
      float v = wave_col_sum(partial + col * nb, lane, nb);
      if (lane == 0) tot[col] = v;
    }
    __syncthreads();
    if (tid == 0) {
      const float dd = dd_p[0];
      float cntv[K], mu[K][C];
#pragma unroll
      for (int k = 0; k < K; ++k) {
        cntv[k] = tot[k];
        const float inv = 1.0f / fmaxf(cntv[k], 1.0f);
#pragma unroll
        for (int c = 0; c < C; ++c) mu[k][c] = tot[K + k * C + c] * inv;
      }
      float ld = 0.f;
#pragma unroll
      for (int a = 0; a < K; ++a) {
#pragma unroll
        for (int b = 0; b < K; ++b) {
          if (a == b) continue;
          float csq = 0.f;
#pragma unroll
          for (int c = 0; c < C; ++c) {
            const float d = mu[a][c] - mu[b][c];
            csq = fmaf(d, d, csq);
          }
          const float cd = csq > 0.f ? sqrtf(csq) : 0.f;
          const float dh = fmaxf(dd - cd, 0.f);
          ld = fmaf(dh, dh, ld);
        }
      }
      ld *= 1.0f / (float)(K * (K - 1));
#pragma unroll
      for (int k = 0; k < K; ++k) atomicExch(&finals[k], cntv[k]);
#pragma unroll
      for (int k = 0; k < K; ++k)
#pragma unroll
        for (int c = 0; c < C; ++c) atomicExch(&finals[K + k * C + c], mu[k][c]);
      atomicExch(&finals[25], ld);
      __threadfence();        // order finals exchanges before flag
      atomicExch(flag1, 1);   // release
    }
  }

  // all blocks wait for centroids (concurrent device-scope loads, no RMW)
  if (tid == 0) {
    while (__hip_atomic_load(flag1, __ATOMIC_RELAXED,
                             __HIP_MEMORY_SCOPE_AGENT) == 0)
      __builtin_amdgcn_s_sleep(2);
  }
  __syncthreads();

  // ---------- Phase C: hinge on REGISTER-resident pixels ----------
  __shared__ float smu[K * C];
  if (tid < K * C)
    smu[tid] = __hip_atomic_load(&finals[K + tid], __ATOMIC_RELAXED,
                                 __HIP_MEMORY_SCOPE_AGENT);
  __syncthreads();
  const float dv = dv_p[0];

  float vs[K] = {};
#pragma unroll
  for (int p = 0; p < PPT; ++p) {
    const int l = labv[p];
    if (l >= 0) {
      const float d0 = smu[l * C + 0] - x[p][0];
      const float d1 = smu[l * C + 1] - x[p][1];
      const float d2 = smu[l * C + 2] - x[p][2];
      const float d3 = smu[l * C + 3] - x[p][3];
      float dsq = d0 * d0;
      dsq = fmaf(d1, d1, dsq);
      dsq = fmaf(d2, d2, dsq);
      dsq = fmaf(d3, d3, dsq);
      const float dn = dsq > 0.f ? sqrtf(dsq) : 0.f;
      const float h  = fmaxf(dn - dv, 0.f);
      const float var = h * h;
#pragma unroll
      for (int k = 0; k < K; ++k) vs[k] += (l == k) ? var : 0.f;
    }
  }

  __shared__ float red2[TPB / 64][K];
#pragma unroll
  for (int j = 0; j < K; ++j) {
    float v = wave_reduce_sum(vs[j]);
    if (lane == 0) red2[wave][j] = v;
  }
  __syncthreads();
  if (tid < K) {
    float t = red2[0][tid] + red2[1][tid] + red2[2][tid] + red2[3][tid];
    atomicExch(&vpart[tid * nb + bid], t);
  }
  __syncthreads();  // exchanges complete

  // ---------- Barrier B: last block -> final scalar ----------
  __shared__ int lastB;
  if (tid == 0) lastB = hier_arrive_last(gtick2, stick2, bid, nb) ? 1 : 0;
  __syncthreads();
  if (!lastB) return;

  __threadfence();  // acquire (one block)
  __shared__ float tot2[K];
  for (int col = wave; col < K; col += TPB / 64) {
    float v = wave_col_sum(vpart + col * nb, lane, nb);
    if (lane == 0) tot2[col] = v;
  }
  __syncthreads();
  if (tid == 0) {
    float lvar = 0.f;
#pragma unroll
    for (int k = 0; k < K; ++k) lvar += tot2[k] / fmaxf(finals[k], 1.0f);
    lvar *= 1.0f / (float)K;
    out[0] = lvar + finals[25];
  }
}

// ======================= fallback: proven round-3 pipeline =======================
constexpr int RED_TPB = 1024;

__global__ __launch_bounds__(TPB) void k_stats(
    const float* __restrict__ pred, const int* __restrict__ lab,
    float* __restrict__ partial, int HW) {
  const int tid = threadIdx.x;
  float cnt[K] = {0.f, 0.f, 0.f, 0.f, 0.f};
  float sum[K][C] = {};
  const long long chunk_stride = (long long)NB * TPB * PPT;
  for (long long chunk = (long long)blockIdx.x * TPB * PPT; chunk < HW;
       chunk += chunk_stride) {
    const long long p0 = chunk + (long long)tid * PPT;
    if (p0 + PPT <= HW) {
      int4 la = *reinterpret_cast<const int4*>(lab + p0);
      int4 lb = *reinterpret_cast<const int4*>(lab + p0 + 4);
      int labv[PPT] = {la.x, la.y, la.z, la.w, lb.x, lb.y, lb.z, lb.w};
      float x[PPT][C];
#pragma unroll
      for (int c = 0; c < C; ++c) {
        const float* base = pred + (long long)c * HW + p0;
        float4 a = *reinterpret_cast<const float4*>(base);
        float4 b = *reinterpret_cast<const float4*>(base + 4);
        x[0][c]=a.x; x[1][c]=a.y; x[2][c]=a.z; x[3][c]=a.w;
        x[4][c]=b.x; x[5][c]=b.y; x[6][c]=b.z; x[7][c]=b.w;
      }
#pragma unroll
      for (int p = 0; p < PPT; ++p) {
        const int l = labv[p];
#pragma unroll
        for (int k = 0; k < K; ++k) {
          const float m = (l == k) ? 1.0f : 0.0f;
          cnt[k] += m;
#pragma unroll
          for (int c = 0; c < C; ++c) sum[k][c] = fmaf(m, x[p][c], sum[k][c]);
        }
      }
    } else if (p0 < HW) {
      for (int p = 0; p < PPT && p0 + p < HW; ++p) {
        const int l = lab[p0 + p];
        for (int k = 0; k < K; ++k) {
          const float m = (l == k) ? 1.0f : 0.0f;
          cnt[k] += m;
          for (int c = 0; c < C; ++c)
            sum[k][c] = fmaf(m, pred[(long long)c * HW + p0 + p], sum[k][c]);
        }
      }
    }
  }
  __shared__ float red[TPB / 64][25];
  const int wave = tid >> 6, lane = tid & 63;
#pragma unroll
  for (int j = 0; j < 25; ++j) {
    float v = (j < K) ? cnt[j] : sum[(j - K) >> 2][(j - K) & 3];
    v = wave_reduce_sum(v);
    if (lane == 0) red[wave][j] = v;
  }
  __syncthreads();
  if (tid < 25) {
    float t = red[0][tid] + red[1][tid] + red[2][tid] + red[3][tid];
    partial[tid * NB + blockIdx.x] = t;
  }
}

__global__ __launch_bounds__(RED_TPB) void k_centroids(
    const float* __restrict__ partial, const float* __restrict__ dd_p,
    float* __restrict__ finals) {
  __shared__ float tot[25];
  const int tid = threadIdx.x, wave = tid >> 6, lane = tid & 63;
  for (int col = wave; col < 25; col += RED_TPB / 64) {
    float v = wave_col_sum(partial + col * NB, lane, NB);
    if (lane == 0) tot[col] = v;
  }
  __syncthreads();
  if (tid == 0) {
    const float dd = dd_p[0];
    float cnt[K], mu[K][C];
#pragma unroll
    for (int k = 0; k < K; ++k) {
      cnt[k] = tot[k];
      const float inv = 1.0f / fmaxf(cnt[k], 1.0f);
#pragma unroll
      for (int c = 0; c < C; ++c) mu[k][c] = tot[K + k * C + c] * inv;
    }
    float ld = 0.f;
#pragma unroll
    for (int a = 0; a < K; ++a)
#pragma unroll
      for (int b = 0; b < K; ++b) {
        if (a == b) continue;
        float csq = 0.f;
#pragma unroll
        for (int c = 0; c < C; ++c) {
          const float d = mu[a][c] - mu[b][c];
          csq = fmaf(d, d, csq);
        }
        const float cd = csq > 0.f ? sqrtf(csq) : 0.f;
        const float dh = fmaxf(dd - cd, 0.f);
        ld = fmaf(dh, dh, ld);
      }
    ld *= 1.0f / (float)(K * (K - 1));
#pragma unroll
    for (int k = 0; k < K; ++k) finals[k] = cnt[k];
#pragma unroll
    for (int k = 0; k < K; ++k)
#pragma unroll
      for (int c = 0; c < C; ++c) finals[K + k * C + c] = mu[k][c];
    finals[25] = ld;
  }
}

__global__ __launch_bounds__(TPB) void k_var(
    const float* __restrict__ pred, const int* __restrict__ lab,
    const float* __restrict__ finals, const float* __restrict__ dv_p,
    float* __restrict__ vpartial, int HW) {
  __shared__ __align__(16) float smu[K * C];
  if (threadIdx.x < K * C) smu[threadIdx.x] = finals[K + threadIdx.x];
  __syncthreads();
  const float dv = dv_p[0];
  const int tid = threadIdx.x;
  float vs[K] = {};
  const long long chunk_stride = (long long)NB * TPB * PPT;
  for (long long chunk = (long long)blockIdx.x * TPB * PPT; chunk < HW;
       chunk += chunk_stride) {
    const long long p0 = chunk + (long long)tid * PPT;
    if (p0 + PPT <= HW) {
      int4 la = *reinterpret_cast<const int4*>(lab + p0);
      int4 lb = *reinterpret_cast<const int4*>(lab + p0 + 4);
      int labv[PPT] = {la.x, la.y, la.z, la.w, lb.x, lb.y, lb.z, lb.w};
      float x[PPT][C];
#pragma unroll
      for (int c = 0; c < C; ++c) {
        const float* base = pred + (long long)c * HW + p0;
        float4 a = *reinterpret_cast<const float4*>(base);
        float4 b = *reinterpret_cast<const float4*>(base + 4);
        x[0][c]=a.x; x[1][c]=a.y; x[2][c]=a.z; x[3][c]=a.w;
        x[4][c]=b.x; x[5][c]=b.y; x[6][c]=b.z; x[7][c]=b.w;
      }
#pragma unroll
      for (int p = 0; p < PPT; ++p) {
        const int l = labv[p];
        const float4 mu = *reinterpret_cast<const float4*>(&smu[l * C]);
        const float d0 = mu.x - x[p][0];
        const float d1 = mu.y - x[p][1];
        const float d2 = mu.z - x[p][2];
        const float d3 = mu.w - x[p][3];
        float dsq = d0 * d0;
        dsq = fmaf(d1, d1, dsq);
        dsq = fmaf(d2, d2, dsq);
        dsq = fmaf(d3, d3, dsq);
        const float dn = dsq > 0.f ? sqrtf(dsq) : 0.f;
        const float h  = fmaxf(dn - dv, 0.f);
        const float var = h * h;
#pragma unroll
        for (int k = 0; k < K; ++k) vs[k] += (l == k) ? var : 0.f;
      }
    } else if (p0 < HW) {
      for (int p = 0; p < PPT && p0 + p < HW; ++p) {
        const int l = lab[p0 + p];
        float dsq = 0.f;
        for (int c = 0; c < C; ++c) {
          const float d = smu[l * C + c] - pred[(long long)c * HW + p0 + p];
          dsq = fmaf(d, d, dsq);
        }
        const float dn = dsq > 0.f ? sqrtf(dsq) : 0.f;
        const float h  = fmaxf(dn - dv, 0.f);
        const float var = h * h;
        for (int k = 0; k < K; ++k) vs[k] += (l == k) ? var : 0.f;
      }
    }
  }
  __shared__ float red[TPB / 64][K];
  const int wave = tid >> 6, lane = tid & 63;
#pragma unroll
  for (int j = 0; j < K; ++j) {
    float v = wave_reduce_sum(vs[j]);
    if (lane == 0) red[wave][j] = v;
  }
  __syncthreads();
  if (tid < K) {
    float t = red[0][tid] + red[1][tid] + red[2][tid] + red[3][tid];
    vpartial[tid * NB + blockIdx.x] = t;
  }
}

__global__ __launch_bounds__(RED_TPB) void k_final(
    const float* __restrict__ vpartial, const float* __restrict__ finals,
    float* __restrict__ out) {
  __shared__ float tot[K];
  const int tid = threadIdx.x, wave = tid >> 6, lane = tid & 63;
  if (wave < K) {
    float v = wave_col_sum(vpartial + wave * NB, lane, NB);
    if (lane == 0) tot[wave] = v;
  }
  __syncthreads();
  if (tid == 0) {
    float lvar = 0.f;
#pragma unroll
    for (int k = 0; k < K; ++k) lvar += tot[k] / fmaxf(finals[k], 1.0f);
    lvar *= 1.0f / (float)K;
    out[0] = lvar + finals[25];
  }
}

extern "C" void kernel_launch(void* const* d_in, const int* in_sizes, int n_in,
                              void* d_out, int out_size, void* d_ws, size_t ws_size,
                              hipStream_t stream) {
  const float* pred = (const float*)d_in[0];
  const int*   lab  = (const int*)d_in[1];
  const float* dv   = (const float*)d_in[2];
  const float* dd   = (const float*)d_in[3];
  float*       out  = (float*)d_out;

  const int HW = in_sizes[1];  // 1024*2048 = 2^21

  float* ws     = (float*)d_ws;
  float* part1  = ws;                 // 25 * NB floats
  float* finals = ws + 25 * NB;       // 26 floats (pad 32)
  float* vpart  = ws + 25 * NB + 32;  // K * NB floats
  int*   bar    = (int*)(ws + 25 * NB + 32 + K * NB);
  const int bar_ints = 2 * NGROUP * GSTRIDE + 64;

  hipMemsetAsync(bar, 0, bar_ints * sizeof(int), stream);

  void* args[] = {(void*)&pred, (void*)&lab, (void*)&dv, (void*)&dd,
                  (void*)&part1, (void*)&finals, (void*)&vpart,
                  (void*)&bar, (void*)&out, (void*)&HW};
  hipError_t err = hipLaunchCooperativeKernel(
      (const void*)k_fused, dim3(NB), dim3(TPB), args, 0, stream);

  if (err != hipSuccess) {
    // fallback: proven round-3 pipeline (33.3 us)
    k_stats    <<<NB, TPB, 0, stream>>>(pred, lab, part1, HW);
    k_centroids<<<1,  RED_TPB, 0, stream>>>(part1, dd, finals);
    k_var      <<<NB, TPB, 0, stream>>>(pred, lab, finals, dv, vpart, HW);
    k_final    <<<1,  RED_TPB, 0, stream>>>(vpart, finals, out);
  }
}

// Round 10
// 63.088 us; speedup vs baseline: 1.0254x; 1.0254x over previous
//
#include <hip/hip_runtime.h>

// cluster (discriminative) loss: L_var + L_dist, C=4, K=5.
// Cooperative single kernel, pixels register-resident across both phases.
// EVERY hot sync address is distributed (R4/R5/R9 lesson: same-address
// coherence-point ops serialize at ~27ns; storms of them jam the fabric):
//   arrive:    hierarchical 32x32 ticket (distinct 64B lines)      [R6-proven]
//   broadcast: finisher replicates mu into 32 per-group copies and
//              sets 32 per-group flags (32 pollers/line, slow poll)
//   publish:   atomicExch to per-block slots                       [R6-proven]
//   acquire:   __threadfence() only in the finisher blocks         [R4 lesson]
// Fallback: proven round-3 4-kernel pipeline (33.3us) if coop launch fails.

constexpr int K   = 5;
constexpr int C   = 4;
constexpr int TPB = 256;
constexpr int PPT = 8;
constexpr int NB  = 1024;      // 1024*256*8 = 2^21 = HW exactly
constexpr int NGROUP  = 32;
constexpr int GSTRIDE = 16;    // 64B between counters

// bar layout (ints): gtick1 @0 (32x16), stick1 @512, gtick2 @528 (32x16),
// stick2 @1040, flags @1056 (32x16). total 1568 ints.
constexpr int BAR_GT1   = 0;
constexpr int BAR_ST1   = 512;
constexpr int BAR_GT2   = 528;
constexpr int BAR_ST2   = 1040;
constexpr int BAR_FLAGS = 1056;
constexpr int BAR_INTS  = 1568;

__device__ __forceinline__ float wave_reduce_sum(float v) {
#pragma unroll
  for (int off = 32; off > 0; off >>= 1) v += __shfl_down(v, off, 64);
  return v;
}

__device__ __forceinline__ float wave_col_sum(const float* __restrict__ colp,
                                              int lane, int nb) {
  const float4* p4 = reinterpret_cast<const float4*>(colp);
  float s = 0.f;
  for (int r = lane; r < (nb >> 2); r += 64) {
    float4 a = p4[r];
    s += (a.x + a.y) + (a.z + a.w);
  }
  return wave_reduce_sum(s);
}

__device__ __forceinline__ bool hier_arrive_last(int* __restrict__ gtick,
                                                 int* __restrict__ stick,
                                                 int bid, int nb) {
  const int g = atomicAdd(&gtick[(bid & (NGROUP - 1)) * GSTRIDE], 1);
  if (g == nb / NGROUP - 1) return atomicAdd(stick, 1) == NGROUP - 1;
  return false;
}

// ======================= fused cooperative kernel =======================
__global__ __launch_bounds__(TPB, 4) void k_fused(
    const float* __restrict__ pred, const int* __restrict__ lab,
    const float* __restrict__ dv_p, const float* __restrict__ dd_p,
    float* __restrict__ partial, float* __restrict__ finals,
    float* __restrict__ vpart, float* __restrict__ fcopy,
    int* __restrict__ bar, float* __restrict__ out, int HW) {
  const int tid = threadIdx.x, bid = blockIdx.x;
  const int wave = tid >> 6, lane = tid & 63;
  const int nb = gridDim.x;
  const int grp = bid & (NGROUP - 1);

  int* gtick1 = bar + BAR_GT1;
  int* stick1 = bar + BAR_ST1;
  int* gtick2 = bar + BAR_GT2;
  int* stick2 = bar + BAR_ST2;
  int* flags  = bar + BAR_FLAGS;

  // ---------- Phase A: load ONCE into registers; per-thread stats ----------
  const long long p0 = ((long long)bid * TPB + tid) * PPT;
  float x[PPT][C];
  int labv[PPT];
  if (p0 + PPT <= HW) {
    int4 la = *reinterpret_cast<const int4*>(lab + p0);
    int4 lb = *reinterpret_cast<const int4*>(lab + p0 + 4);
    labv[0]=la.x; labv[1]=la.y; labv[2]=la.z; labv[3]=la.w;
    labv[4]=lb.x; labv[5]=lb.y; labv[6]=lb.z; labv[7]=lb.w;
#pragma unroll
    for (int c = 0; c < C; ++c) {
      const float* base = pred + (long long)c * HW + p0;
      float4 a = *reinterpret_cast<const float4*>(base);
      float4 b = *reinterpret_cast<const float4*>(base + 4);
      x[0][c]=a.x; x[1][c]=a.y; x[2][c]=a.z; x[3][c]=a.w;
      x[4][c]=b.x; x[5][c]=b.y; x[6][c]=b.z; x[7][c]=b.w;
    }
  } else {
#pragma unroll
    for (int p = 0; p < PPT; ++p) {
      if (p0 + p < HW) {
        labv[p] = lab[p0 + p];
#pragma unroll
        for (int c = 0; c < C; ++c) x[p][c] = pred[(long long)c * HW + p0 + p];
      } else {
        labv[p] = -1;
#pragma unroll
        for (int c = 0; c < C; ++c) x[p][c] = 0.f;
      }
    }
  }

  float cnt[K] = {0.f, 0.f, 0.f, 0.f, 0.f};
  float sum[K][C] = {};
#pragma unroll
  for (int p = 0; p < PPT; ++p) {
    const int l = labv[p];
#pragma unroll
    for (int k = 0; k < K; ++k) {
      const float m = (l == k) ? 1.0f : 0.0f;
      cnt[k] += m;
#pragma unroll
      for (int c = 0; c < C; ++c) sum[k][c] = fmaf(m, x[p][c], sum[k][c]);
    }
  }

  __shared__ float red[TPB / 64][25];
#pragma unroll
  for (int j = 0; j < 25; ++j) {
    float v = (j < K) ? cnt[j] : sum[(j - K) >> 2][(j - K) & 3];
    v = wave_reduce_sum(v);
    if (lane == 0) red[wave][j] = v;
  }
  __syncthreads();
  if (tid < 25) {
    float t = red[0][tid] + red[1][tid] + red[2][tid] + red[3][tid];
    atomicExch(&partial[tid * nb + bid], t);  // publish at coherence point
  }
  __syncthreads();  // drains vmcnt(0): exchanges complete before arrival

  // ---------- Barrier A: last block -> centroids, replicate, flags ----------
  __shared__ int lastA;
  if (tid == 0) lastA = hier_arrive_last(gtick1, stick1, bid, nb) ? 1 : 0;
  __syncthreads();
  if (lastA) {
    __threadfence();  // acquire (this block only)
    __shared__ float tot[25];
    __shared__ float muS[21];  // [0..19]=mu, [20]=L_dist
    for (int col = wave; col < 25; col += TPB / 64) {
      float v = wave_col_sum(partial + col * nb, lane, nb);
      if (lane == 0) tot[col] = v;
    }
    __syncthreads();
    if (tid == 0) {
      const float dd = dd_p[0];
      float cntv[K], mu[K][C];
#pragma unroll
      for (int k = 0; k < K; ++k) {
        cntv[k] = tot[k];
        const float inv = 1.0f / fmaxf(cntv[k], 1.0f);
#pragma unroll
        for (int c = 0; c < C; ++c) mu[k][c] = tot[K + k * C + c] * inv;
      }
      float ld = 0.f;
#pragma unroll
      for (int a = 0; a < K; ++a) {
#pragma unroll
        for (int b = 0; b < K; ++b) {
          if (a == b) continue;
          float csq = 0.f;
#pragma unroll
          for (int c = 0; c < C; ++c) {
            const float d = mu[a][c] - mu[b][c];
            csq = fmaf(d, d, csq);
          }
          const float cd = csq > 0.f ? sqrtf(csq) : 0.f;
          const float dh = fmaxf(dd - cd, 0.f);
          ld = fmaf(dh, dh, ld);
        }
      }
      ld *= 1.0f / (float)(K * (K - 1));
      // finals for the LAST finisher (counts + L_dist)
#pragma unroll
      for (int k = 0; k < K; ++k) atomicExch(&finals[k], cntv[k]);
      atomicExch(&finals[25], ld);
#pragma unroll
      for (int k = 0; k < K; ++k)
#pragma unroll
        for (int c = 0; c < C; ++c) muS[k * C + c] = mu[k][c];
      muS[20] = ld;
    }
    __syncthreads();
    // replicate mu into 32 per-group copies (distinct lines), in parallel
    for (int idx = tid; idx < NGROUP * 20; idx += TPB) {
      const int g = idx / 20, j = idx % 20;
      atomicExch(&fcopy[g * 32 + j], muS[j]);
    }
    __syncthreads();  // drain: copies complete before flags
    if (tid < NGROUP) atomicExch(&flags[tid * GSTRIDE], 1);
  }

  // ---------- all blocks wait on their GROUP flag (32 pollers/line) ----------
  if (tid == 0) {
    while (__hip_atomic_load(&flags[grp * GSTRIDE], __ATOMIC_RELAXED,
                             __HIP_MEMORY_SCOPE_AGENT) == 0)
      __builtin_amdgcn_s_sleep(32);   // ~2k cycles between polls
  }
  __syncthreads();

  // ---------- Phase C: hinge on REGISTER-resident pixels ----------
  __shared__ float smu[20];
  if (tid < 20)
    smu[tid] = __hip_atomic_load(&fcopy[grp * 32 + tid], __ATOMIC_RELAXED,
                                 __HIP_MEMORY_SCOPE_AGENT);
  __syncthreads();
  const float dv = dv_p[0];

  float vs[K] = {};
#pragma unroll
  for (int p = 0; p < PPT; ++p) {
    const int l = labv[p];
    if (l >= 0) {
      const float d0 = smu[l * C + 0] - x[p][0];
      const float d1 = smu[l * C + 1] - x[p][1];
      const float d2 = smu[l * C + 2] - x[p][2];
      const float d3 = smu[l * C + 3] - x[p][3];
      float dsq = d0 * d0;
      dsq = fmaf(d1, d1, dsq);
      dsq = fmaf(d2, d2, dsq);
      dsq = fmaf(d3, d3, dsq);
      const float dn = dsq > 0.f ? sqrtf(dsq) : 0.f;
      const float h  = fmaxf(dn - dv, 0.f);
      const float var = h * h;
#pragma unroll
      for (int k = 0; k < K; ++k) vs[k] += (l == k) ? var : 0.f;
    }
  }

  __shared__ float red2[TPB / 64][K];
#pragma unroll
  for (int j = 0; j < K; ++j) {
    float v = wave_reduce_sum(vs[j]);
    if (lane == 0) red2[wave][j] = v;
  }
  __syncthreads();
  if (tid < K) {
    float t = red2[0][tid] + red2[1][tid] + red2[2][tid] + red2[3][tid];
    atomicExch(&vpart[tid * nb + bid], t);
  }
  __syncthreads();  // exchanges complete before arrival

  // ---------- Barrier B: last block -> final scalar ----------
  __shared__ int lastB;
  if (tid == 0) lastB = hier_arrive_last(gtick2, stick2, bid, nb) ? 1 : 0;
  __syncthreads();
  if (!lastB) return;

  __threadfence();  // acquire (one block)
  __shared__ float tot2[K];
  for (int col = wave; col < K; col += TPB / 64) {
    float v = wave_col_sum(vpart + col * nb, lane, nb);
    if (lane == 0) tot2[col] = v;
  }
  __syncthreads();
  if (tid == 0) {
    float lvar = 0.f;
#pragma unroll
    for (int k = 0; k < K; ++k) lvar += tot2[k] / fmaxf(finals[k], 1.0f);
    lvar *= 1.0f / (float)K;
    out[0] = lvar + finals[25];
  }
}

// ======================= fallback: proven round-3 pipeline =======================
constexpr int RED_TPB = 1024;

__global__ __launch_bounds__(TPB) void k_stats(
    const float* __restrict__ pred, const int* __restrict__ lab,
    float* __restrict__ partial, int HW) {
  const int tid = threadIdx.x;
  float cnt[K] = {0.f, 0.f, 0.f, 0.f, 0.f};
  float sum[K][C] = {};
  const long long chunk_stride = (long long)NB * TPB * PPT;
  for (long long chunk = (long long)blockIdx.x * TPB * PPT; chunk < HW;
       chunk += chunk_stride) {
    const long long p0 = chunk + (long long)tid * PPT;
    if (p0 + PPT <= HW) {
      int4 la = *reinterpret_cast<const int4*>(lab + p0);
      int4 lb = *reinterpret_cast<const int4*>(lab + p0 + 4);
      int labv[PPT] = {la.x, la.y, la.z, la.w, lb.x, lb.y, lb.z, lb.w};
      float x[PPT][C];
#pragma unroll
      for (int c = 0; c < C; ++c) {
        const float* base = pred + (long long)c * HW + p0;
        float4 a = *reinterpret_cast<const float4*>(base);
        float4 b = *reinterpret_cast<const float4*>(base + 4);
        x[0][c]=a.x; x[1][c]=a.y; x[2][c]=a.z; x[3][c]=a.w;
        x[4][c]=b.x; x[5][c]=b.y; x[6][c]=b.z; x[7][c]=b.w;
      }
#pragma unroll
      for (int p = 0; p < PPT; ++p) {
        const int l = labv[p];
#pragma unroll
        for (int k = 0; k < K; ++k) {
          const float m = (l == k) ? 1.0f : 0.0f;
          cnt[k] += m;
#pragma unroll
          for (int c = 0; c < C; ++c) sum[k][c] = fmaf(m, x[p][c], sum[k][c]);
        }
      }
    } else if (p0 < HW) {
      for (int p = 0; p < PPT && p0 + p < HW; ++p) {
        const int l = lab[p0 + p];
        for (int k = 0; k < K; ++k) {
          const float m = (l == k) ? 1.0f : 0.0f;
          cnt[k] += m;
          for (int c = 0; c < C; ++c)
            sum[k][c] = fmaf(m, pred[(long long)c * HW + p0 + p], sum[k][c]);
        }
      }
    }
  }
  __shared__ float red[TPB / 64][25];
  const int wave = tid >> 6, lane = tid & 63;
#pragma unroll
  for (int j = 0; j < 25; ++j) {
    float v = (j < K) ? cnt[j] : sum[(j - K) >> 2][(j - K) & 3];
    v = wave_reduce_sum(v);
    if (lane == 0) red[wave][j] = v;
  }
  __syncthreads();
  if (tid < 25) {
    float t = red[0][tid] + red[1][tid] + red[2][tid] + red[3][tid];
    partial[tid * NB + blockIdx.x] = t;
  }
}

__global__ __launch_bounds__(RED_TPB) void k_centroids(
    const float* __restrict__ partial, const float* __restrict__ dd_p,
    float* __restrict__ finals) {
  __shared__ float tot[25];
  const int tid = threadIdx.x, wave = tid >> 6, lane = tid & 63;
  for (int col = wave; col < 25; col += RED_TPB / 64) {
    float v = wave_col_sum(partial + col * NB, lane, NB);
    if (lane == 0) tot[col] = v;
  }
  __syncthreads();
  if (tid == 0) {
    const float dd = dd_p[0];
    float cnt[K], mu[K][C];
#pragma unroll
    for (int k = 0; k < K; ++k) {
      cnt[k] = tot[k];
      const float inv = 1.0f / fmaxf(cnt[k], 1.0f);
#pragma unroll
      for (int c = 0; c < C; ++c) mu[k][c] = tot[K + k * C + c] * inv;
    }
    float ld = 0.f;
#pragma unroll
    for (int a = 0; a < K; ++a)
#pragma unroll
      for (int b = 0; b < K; ++b) {
        if (a == b) continue;
        float csq = 0.f;
#pragma unroll
        for (int c = 0; c < C; ++c) {
          const float d = mu[a][c] - mu[b][c];
          csq = fmaf(d, d, csq);
        }
        const float cd = csq > 0.f ? sqrtf(csq) : 0.f;
        const float dh = fmaxf(dd - cd, 0.f);
        ld = fmaf(dh, dh, ld);
      }
    ld *= 1.0f / (float)(K * (K - 1));
#pragma unroll
    for (int k = 0; k < K; ++k) finals[k] = cnt[k];
#pragma unroll
    for (int k = 0; k < K; ++k)
#pragma unroll
      for (int c = 0; c < C; ++c) finals[K + k * C + c] = mu[k][c];
    finals[25] = ld;
  }
}

__global__ __launch_bounds__(TPB) void k_var(
    const float* __restrict__ pred, const int* __restrict__ lab,
    const float* __restrict__ finals, const float* __restrict__ dv_p,
    float* __restrict__ vpartial, int HW) {
  __shared__ __align__(16) float smu[K * C];
  if (threadIdx.x < K * C) smu[threadIdx.x] = finals[K + threadIdx.x];
  __syncthreads();
  const float dv = dv_p[0];
  const int tid = threadIdx.x;
  float vs[K] = {};
  const long long chunk_stride = (long long)NB * TPB * PPT;
  for (long long chunk = (long long)blockIdx.x * TPB * PPT; chunk < HW;
       chunk += chunk_stride) {
    const long long p0 = chunk + (long long)tid * PPT;
    if (p0 + PPT <= HW) {
      int4 la = *reinterpret_cast<const int4*>(lab + p0);
      int4 lb = *reinterpret_cast<const int4*>(lab + p0 + 4);
      int labv[PPT] = {la.x, la.y, la.z, la.w, lb.x, lb.y, lb.z, lb.w};
      float x[PPT][C];
#pragma unroll
      for (int c = 0; c < C; ++c) {
        const float* base = pred + (long long)c * HW + p0;
        float4 a = *reinterpret_cast<const float4*>(base);
        float4 b = *reinterpret_cast<const float4*>(base + 4);
        x[0][c]=a.x; x[1][c]=a.y; x[2][c]=a.z; x[3][c]=a.w;
        x[4][c]=b.x; x[5][c]=b.y; x[6][c]=b.z; x[7][c]=b.w;
      }
#pragma unroll
      for (int p = 0; p < PPT; ++p) {
        const int l = labv[p];
        const float4 mu = *reinterpret_cast<const float4*>(&smu[l * C]);
        const float d0 = mu.x - x[p][0];
        const float d1 = mu.y - x[p][1];
        const float d2 = mu.z - x[p][2];
        const float d3 = mu.w - x[p][3];
        float dsq = d0 * d0;
        dsq = fmaf(d1, d1, dsq);
        dsq = fmaf(d2, d2, dsq);
        dsq = fmaf(d3, d3, dsq);
        const float dn = dsq > 0.f ? sqrtf(dsq) : 0.f;
        const float h  = fmaxf(dn - dv, 0.f);
        const float var = h * h;
#pragma unroll
        for (int k = 0; k < K; ++k) vs[k] += (l == k) ? var : 0.f;
      }
    } else if (p0 < HW) {
      for (int p = 0; p < PPT && p0 + p < HW; ++p) {
        const int l = lab[p0 + p];
        float dsq = 0.f;
        for (int c = 0; c < C; ++c) {
          const float d = smu[l * C + c] - pred[(long long)c * HW + p0 + p];
          dsq = fmaf(d, d, dsq);
        }
        const float dn = dsq > 0.f ? sqrtf(dsq) : 0.f;
        const float h  = fmaxf(dn - dv, 0.f);
        const float var = h * h;
        for (int k = 0; k < K; ++k) vs[k] += (l == k) ? var : 0.f;
      }
    }
  }
  __shared__ float red[TPB / 64][K];
  const int wave = tid >> 6, lane = tid & 63;
#pragma unroll
  for (int j = 0; j < K; ++j) {
    float v = wave_reduce_sum(vs[j]);
    if (lane == 0) red[wave][j] = v;
  }
  __syncthreads();
  if (tid < K) {
    float t = red[0][tid] + red[1][tid] + red[2][tid] + red[3][tid];
    vpartial[tid * NB + blockIdx.x] = t;
  }
}

__global__ __launch_bounds__(RED_TPB) void k_final(
    const float* __restrict__ vpartial, const float* __restrict__ finals,
    float* __restrict__ out) {
  __shared__ float tot[K];
  const int tid = threadIdx.x, wave = tid >> 6, lane = tid & 63;
  if (wave < K) {
    float v = wave_col_sum(vpartial + wave * NB, lane, NB);
    if (lane == 0) tot[wave] = v;
  }
  __syncthreads();
  if (tid == 0) {
    float lvar = 0.f;
#pragma unroll
    for (int k = 0; k < K; ++k) lvar += tot[k] / fmaxf(finals[k], 1.0f);
    lvar *= 1.0f / (float)K;
    out[0] = lvar + finals[25];
  }
}

extern "C" void kernel_launch(void* const* d_in, const int* in_sizes, int n_in,
                              void* d_out, int out_size, void* d_ws, size_t ws_size,
                              hipStream_t stream) {
  const float* pred = (const float*)d_in[0];
  const int*   lab  = (const int*)d_in[1];
  const float* dv   = (const float*)d_in[2];
  const float* dd   = (const float*)d_in[3];
  float*       out  = (float*)d_out;

  const int HW = in_sizes[1];  // 1024*2048 = 2^21

  float* ws     = (float*)d_ws;
  float* part1  = ws;                           // 25*NB floats
  float* finals = ws + 25 * NB;                 // 26 floats (pad 32)
  float* vpart  = ws + 25 * NB + 32;            // K*NB floats
  float* fcopy  = ws + 25 * NB + 32 + K * NB;   // 32 copies x 32 floats
  int*   bar    = (int*)(fcopy + NGROUP * 32);  // BAR_INTS ints

  hipMemsetAsync(bar, 0, BAR_INTS * sizeof(int), stream);

  void* args[] = {(void*)&pred, (void*)&lab, (void*)&dv, (void*)&dd,
                  (void*)&part1, (void*)&finals, (void*)&vpart,
                  (void*)&fcopy, (void*)&bar, (void*)&out, (void*)&HW};
  hipError_t err = hipLaunchCooperativeKernel(
      (const void*)k_fused, dim3(NB), dim3(TPB), args, 0, stream);

  if (err != hipSuccess) {
    // fallback: proven round-3 pipeline (33.3 us)
    k_stats    <<<NB, TPB, 0, stream>>>(pred, lab, part1, HW);
    k_centroids<<<1,  RED_TPB, 0, stream>>>(part1, dd, finals);
    k_var      <<<NB, TPB, 0, stream>>>(pred, lab, finals, dv, vpart, HW);
    k_final    <<<1,  RED_TPB, 0, stream>>>(vpart, finals, out);
  }
}